// Round 4
// baseline (216.303 us; speedup 1.0000x reference)
//
#include <hip/hip_runtime.h>
#include <math.h>

// Problem dims
constexpr int B   = 16;
constexpr int K   = 64;
constexpr int BK  = B * K;        // 1024
constexpr int IN  = 128;
constexpr int H0  = 192;
constexpr int H1  = 64;
constexpr int UNF = 6;
constexpr float EPS = 1e-8f;
constexpr float DT  = 1.0f / 6.0f;
constexpr float L2E = 1.4426950408889634f;   // log2(e)

static __device__ __forceinline__ float rcpf(float x) {
    return __builtin_amdgcn_rcpf(x);
}
static __device__ __forceinline__ float exp2_fast(float x) {
#if __has_builtin(__builtin_amdgcn_exp2f)
    return __builtin_amdgcn_exp2f(x);   // v_exp_f32
#else
    return exp2f(x);
#endif
}
// sigmoid(z) with z pre-scaled by log2(e): s = 1/(1+2^(-z2)); t = -z2
static __device__ __forceinline__ float sig_from_t(float t) {
    return rcpf(1.0f + exp2_fast(t));
}

// ---------------------------------------------------------------------------
// Prep: (a) pack {relu(w), sig*L2E, sig*mu*L2E, relu(w)*erev} into float4 for
// the three hot matrices; (b) layer-0 input synapse sums [B,H0] (x is shared
// by all K particles and all 6 steps). One kernel, branch on blockIdx.
constexpr int NPACK    = H0 * H0 + H0 * H1 + H1 * H1;  // 53248
constexpr int NPACKBLK = NPACK / 256;                   // 208
__global__ __launch_bounds__(256) void prep_kernel(
    const float* __restrict__ w0,  const float* __restrict__ sig0,
    const float* __restrict__ mu0, const float* __restrict__ erev0,
    const float* __restrict__ iw1, const float* __restrict__ isig1,
    const float* __restrict__ imu1,const float* __restrict__ ierev1,
    const float* __restrict__ w1,  const float* __restrict__ sig1,
    const float* __restrict__ mu1, const float* __restrict__ erev1,
    const float* __restrict__ x,   const float* __restrict__ iw0,
    const float* __restrict__ isig0,const float* __restrict__ imu0,
    const float* __restrict__ ierev0,
    float4* __restrict__ pack0, float4* __restrict__ packi1,
    float4* __restrict__ pack1,
    float* __restrict__ in_num, float* __restrict__ in_den)
{
    __shared__ float xs[IN];
    if (blockIdx.x < NPACKBLK) {
        const int t = blockIdx.x * 256 + threadIdx.x;
        constexpr int N0 = H0 * H0;          // 36864
        constexpr int N1 = H0 * H1;          // 12288
        if (t < N0) {
            const float wv = fmaxf(w0[t], 0.0f);
            pack0[t] = make_float4(wv, sig0[t] * L2E, sig0[t] * mu0[t] * L2E,
                                   wv * erev0[t]);
        } else if (t < N0 + N1) {
            const int u = t - N0;
            const float wv = fmaxf(iw1[u], 0.0f);
            packi1[u] = make_float4(wv, isig1[u] * L2E,
                                    isig1[u] * imu1[u] * L2E, wv * ierev1[u]);
        } else {
            const int u = t - N0 - N1;
            const float wv = fmaxf(w1[u], 0.0f);
            pack1[u] = make_float4(wv, sig1[u] * L2E, sig1[u] * mu1[u] * L2E,
                                   wv * erev1[u]);
        }
    } else {
        const int b = blockIdx.x - NPACKBLK;
        const int h = threadIdx.x;
        if (h < IN) xs[h] = x[b * IN + h];
        __syncthreads();
        if (h < H0) {
            float num = 0.0f, den = 0.0f;
            #pragma unroll 4
            for (int i = 0; i < IN; ++i) {
                const int idx = i * H0 + h;
                const float wv = fmaxf(iw0[idx], 0.0f);
                const float t  = isig0[idx] * L2E * (imu0[idx] - xs[i]);
                const float a  = wv * sig_from_t(t);
                num = fmaf(a, ierev0[idx], num);
                den += a;
            }
            in_num[b * H0 + h] = num;
            in_den[b * H0 + h] = den;
        }
    }
}

// ---------------------------------------------------------------------------
// Fused unfold: 512 blocks x 768 threads; each block owns 2 particle rows
// end-to-end (layer 0 then layer 1; s0 stays in LDS). 2 blocks/CU = 24
// waves/CU (R3's 4-row/256-block config was grid-capped at 12 waves/CU,
// VALUBusy 68% -> latency-bound on quarter-rate exp/rcp). Trade: pack reuse
// halves (L2 demand ~1.8 GB/dispatch ~ 30 TB/s at 60 us, under the 34.5
// ceiling).
//
// Layer 0: subgroup q in 0..3 (192 thr each) handles i in [48q,48q+48) for
// both rows; state transposed vs[i][2] so one ds_read_b64 yields both rows.
// Per-step partial num/den reduced via LDS; threads with q<2 apply the
// update for row q. Layer 1: waves 0..7 split i 8-ways, same 2-row reuse.
__global__ __launch_bounds__(768) void fused_unfold_kernel(
    const float* __restrict__ particles,  // [BK, 256]
    const float* __restrict__ noise0,     // [UNF, BK, H0]
    const float* __restrict__ noise1,     // [UNF, BK, H1]
    const float* __restrict__ gleak0, const float* __restrict__ vleak0,
    const float* __restrict__ cm0,    const float* __restrict__ gdiff0,
    const float* __restrict__ gleak1, const float* __restrict__ vleak1,
    const float* __restrict__ cm1,    const float* __restrict__ gdiff1,
    const float4* __restrict__ pack0,     // [H0*H0]
    const float4* __restrict__ packi1,    // [H0*H1]
    const float4* __restrict__ pack1,     // [H1*H1]
    const float* __restrict__ in_num,     // [B, H0]
    const float* __restrict__ in_den,
    float* __restrict__ outp)             // new_particles region: [BK, 256]
{
    const int tid = threadIdx.x;
    const int h   = tid % H0;             // 0..191
    const int q   = tid / H0;             // 0..3 (i-quarter; q<2 also = row)
    const int bk0 = blockIdx.x * 2;
    const int b   = blockIdx.x >> 5;      // (blockIdx.x*2)/64

    const int h1  = tid & 63;
    const int qq  = tid >> 6;             // wave id 0..11

    __shared__ __align__(8) float vs[H0][2];     // s0 state, [i][m]
    __shared__ float2 part0[4][2][H0];           // [q][m][h] {num,den}
    __shared__ __align__(8) float v1s[H1][2];    // s1 state, [i][m]
    __shared__ float2 part1[8][2][H1];           // [qq][m][h1]

    // ---- Early layer-1 state loads (hidden behind layer-0 compute) ----
    float nz1[UNF];
    if (tid < 128) {                      // qq in {0,1} = row
        v1s[h1][qq] = particles[(bk0 + qq) * 256 + H0 + h1];
        #pragma unroll
        for (int s = 0; s < UNF; ++s)
            nz1[s] = noise1[s * (BK * H1) + (bk0 + qq) * H1 + h1];
    }

    // ---- Layer 0 setup ----
    float nz[UNF];
    if (q < 2) {
        vs[h][q] = particles[(bk0 + q) * 256 + h];
        #pragma unroll
        for (int s = 0; s < UNF; ++s)
            nz[s] = noise0[s * (BK * H0) + (bk0 + q) * H0 + h];
    }

    const float gl    = fmaxf(gleak0[h], 0.0f);
    const float glvl  = gl * vleak0[h];
    const float cinv  = rcpf(fmaxf(cm0[h], 0.0f) + EPS);
    const float gd    = gdiff0[h] * sqrtf(DT);
    const float innum = in_num[b * H0 + h];
    const float inden = in_den[b * H0 + h];
    __syncthreads();

    // ---- Layer 0 unfold ----
    const int ibase = 48 * q;
    for (int step = 0; step < UNF; ++step) {
        float num0 = 0.f, den0 = 0.f, num1 = 0.f, den1 = 0.f;
        #pragma unroll 6
        for (int ii = 0; ii < 48; ++ii) {
            const int i = ibase + ii;
            const float4 p  = pack0[i * H0 + h];   // {wv, sig', smu', wv*er}
            const float2 vv = *(const float2*)&vs[i][0];  // both rows
            const float sa = sig_from_t(fmaf(-p.y, vv.x, p.z));
            num0 = fmaf(sa, p.w, num0);
            den0 = fmaf(sa, p.x, den0);
            const float sb = sig_from_t(fmaf(-p.y, vv.y, p.z));
            num1 = fmaf(sb, p.w, num1);
            den1 = fmaf(sb, p.x, den1);
        }
        part0[q][0][h] = make_float2(num0, den0);
        part0[q][1][h] = make_float2(num1, den1);
        __syncthreads();
        if (q < 2) {                      // thread (q,h) updates row q
            float tn = innum, td = inden;
            #pragma unroll
            for (int j = 0; j < 4; ++j) {
                const float2 t = part0[j][q][h];
                tn += t.x; td += t.y;
            }
            const float vh = vs[h][q];
            const float d  = (glvl + tn - (gl + td) * vh) * cinv;
            vs[h][q] = fmaf(gd, nz[step], fmaf(d, DT, vh));
        }
        __syncthreads();
    }

    // s0 -> new_particles[:, :H0] (own value; no barrier needed)
    if (q < 2) outp[(bk0 + q) * 256 + h] = vs[h][q];

    // ---- Layer 1 (same 2 rows; s0 in LDS) ----
    float gl1 = 0.f, glvl1 = 0.f, cinv1 = 0.f, gd1 = 0.f;
    float in1n[2] = {0.f, 0.f};
    float in1d[2] = {0.f, 0.f};
    if (tid < 512) {                      // waves 0..7: i-split over 192
        gl1   = fmaxf(gleak1[h1], 0.0f);
        glvl1 = gl1 * vleak1[h1];
        cinv1 = rcpf(fmaxf(cm1[h1], 0.0f) + EPS);
        gd1   = gdiff1[h1] * sqrtf(DT);
        #pragma unroll 4
        for (int ii = 0; ii < 24; ++ii) {
            const int i = qq * 24 + ii;
            const float4 p  = packi1[i * H1 + h1];
            const float2 vv = *(const float2*)&vs[i][0];
            const float sa = sig_from_t(fmaf(-p.y, vv.x, p.z));
            in1n[0] = fmaf(sa, p.w, in1n[0]);
            in1d[0] = fmaf(sa, p.x, in1d[0]);
            const float sb = sig_from_t(fmaf(-p.y, vv.y, p.z));
            in1n[1] = fmaf(sb, p.w, in1n[1]);
            in1d[1] = fmaf(sb, p.x, in1d[1]);
        }
    }
    __syncthreads();   // v1s visible

    for (int step = 0; step < UNF; ++step) {
        if (tid < 512) {
            float num[2] = {in1n[0], in1n[1]};
            float den[2] = {in1d[0], in1d[1]};
            #pragma unroll
            for (int ii = 0; ii < 8; ++ii) {
                const int i = qq * 8 + ii;
                const float4 p  = pack1[i * H1 + h1];
                const float2 vv = *(const float2*)&v1s[i][0];
                const float sa = sig_from_t(fmaf(-p.y, vv.x, p.z));
                num[0] = fmaf(sa, p.w, num[0]);
                den[0] = fmaf(sa, p.x, den[0]);
                const float sb = sig_from_t(fmaf(-p.y, vv.y, p.z));
                num[1] = fmaf(sb, p.w, num[1]);
                den[1] = fmaf(sb, p.x, den[1]);
            }
            part1[qq][0][h1] = make_float2(num[0], den[0]);
            part1[qq][1][h1] = make_float2(num[1], den[1]);
        }
        __syncthreads();
        if (tid < 128) {                  // row qq, element h1
            float tn = 0.f, td = 0.f;
            #pragma unroll
            for (int j = 0; j < 8; ++j) {
                const float2 t = part1[j][qq][h1];
                tn += t.x; td += t.y;
            }
            const float vh = v1s[h1][qq];
            const float d  = (glvl1 + tn - (gl1 + td) * vh) * cinv1;
            v1s[h1][qq] = fmaf(gd1, nz1[step], fmaf(d, DT, vh));
        }
        __syncthreads();
    }

    if (tid < 128)
        outp[(bk0 + qq) * 256 + H0 + h1] = v1s[h1][qq];  // s1 -> [:, H0:]
}

// ---------------------------------------------------------------------------
// Finalize: output = softmax(log_weights) weighted mean of s1 over K; pass
// log_weights through. grid: B blocks x 64 threads (one wave).
__global__ __launch_bounds__(64) void finalize_kernel(
    const float* __restrict__ log_weights,  // [B, K]
    const float* __restrict__ newp,         // new_particles region [BK,256]
    float* __restrict__ out_y,              // [B, H1]
    float* __restrict__ out_lw)             // [B, K]
{
    const int t = threadIdx.x;   // used as k, then as h (K == H1 == 64)
    const int b = blockIdx.x;

    const float lw = log_weights[b * K + t];
    out_lw[b * K + t] = lw;

    float mx = lw;
    #pragma unroll
    for (int o = 32; o > 0; o >>= 1) mx = fmaxf(mx, __shfl_xor(mx, o));
    const float e = __expf(lw - mx);
    float s = e;
    #pragma unroll
    for (int o = 32; o > 0; o >>= 1) s += __shfl_xor(s, o);

    __shared__ float wk[K];
    wk[t] = e / s;
    __syncthreads();

    float acc = 0.0f;
    for (int k = 0; k < K; ++k)
        acc = fmaf(wk[k], newp[(b * K + k) * 256 + H0 + t], acc);
    out_y[b * H1 + t] = acc;
}

// ---------------------------------------------------------------------------
extern "C" void kernel_launch(void* const* d_in, const int* in_sizes, int n_in,
                              void* d_out, int out_size, void* d_ws, size_t ws_size,
                              hipStream_t stream) {
    const float* x           = (const float*)d_in[0];
    const float* particles   = (const float*)d_in[1];
    const float* log_weights = (const float*)d_in[2];
    const float* noise0      = (const float*)d_in[3];
    const float* noise1      = (const float*)d_in[4];
    const float* gleak0 = (const float*)d_in[5];
    const float* vleak0 = (const float*)d_in[6];
    const float* cm0    = (const float*)d_in[7];
    const float* iw0    = (const float*)d_in[8];
    const float* isig0  = (const float*)d_in[9];
    const float* imu0   = (const float*)d_in[10];
    const float* ierev0 = (const float*)d_in[11];
    const float* w0     = (const float*)d_in[12];
    const float* sig0   = (const float*)d_in[13];
    const float* mu0    = (const float*)d_in[14];
    const float* erev0  = (const float*)d_in[15];
    const float* gdiff0 = (const float*)d_in[16];
    const float* gleak1 = (const float*)d_in[17];
    const float* vleak1 = (const float*)d_in[18];
    const float* cm1    = (const float*)d_in[19];
    const float* iw1    = (const float*)d_in[20];
    const float* isig1  = (const float*)d_in[21];
    const float* imu1   = (const float*)d_in[22];
    const float* ierev1 = (const float*)d_in[23];
    const float* w1     = (const float*)d_in[24];
    const float* sig1   = (const float*)d_in[25];
    const float* mu1    = (const float*)d_in[26];
    const float* erev1  = (const float*)d_in[27];
    const float* gdiff1 = (const float*)d_in[28];

    float* out    = (float*)d_out;
    float* out_y  = out;                       // [B, H1] = 1024
    float* out_np = out + B * H1;              // [BK, 256] = 262144
    float* out_lw = out + B * H1 + BK * 256;   // [B, K]   = 1024

    // Workspace layout (floats): pack0 | packi1 | pack1 | in_num0 | in_den0
    float* ws      = (float*)d_ws;
    float4* pack0  = (float4*)(ws);                       // 36864 float4
    float4* packi1 = (float4*)(ws + 4 * 36864);           // 12288 float4
    float4* pack1  = (float4*)(ws + 4 * (36864 + 12288)); //  4096 float4
    float*  in_num0 = ws + 4 * (36864 + 12288 + 4096);    // [B, H0]
    float*  in_den0 = in_num0 + B * H0;                   // [B, H0]

    prep_kernel<<<NPACKBLK + B, 256, 0, stream>>>(
        w0, sig0, mu0, erev0, iw1, isig1, imu1, ierev1, w1, sig1, mu1, erev1,
        x, iw0, isig0, imu0, ierev0,
        pack0, packi1, pack1, in_num0, in_den0);

    fused_unfold_kernel<<<BK / 2, 768, 0, stream>>>(
        particles, noise0, noise1,
        gleak0, vleak0, cm0, gdiff0,
        gleak1, vleak1, cm1, gdiff1,
        pack0, packi1, pack1, in_num0, in_den0, out_np);

    finalize_kernel<<<B, 64, 0, stream>>>(log_weights, out_np, out_y, out_lw);
}

// Round 5
// 195.217 us; speedup vs baseline: 1.1080x; 1.1080x over previous
//
#include <hip/hip_runtime.h>
#include <math.h>

// Problem dims
constexpr int B   = 16;
constexpr int K   = 64;
constexpr int BK  = B * K;        // 1024
constexpr int IN  = 128;
constexpr int H0  = 192;
constexpr int H1  = 64;
constexpr int UNF = 6;
constexpr float EPS = 1e-8f;
constexpr float DT  = 1.0f / 6.0f;
constexpr float L2E = 1.4426950408889634f;   // log2(e)

static __device__ __forceinline__ float rcpf(float x) {
    return __builtin_amdgcn_rcpf(x);
}
static __device__ __forceinline__ float exp2_fast(float x) {
#if __has_builtin(__builtin_amdgcn_exp2f)
    return __builtin_amdgcn_exp2f(x);   // v_exp_f32
#else
    return exp2f(x);
#endif
}
// sigmoid(z) with z pre-scaled by log2(e): s = 1/(1+2^(-z2)); t = -z2
static __device__ __forceinline__ float sig_from_t(float t) {
    return rcpf(1.0f + exp2_fast(t));
}

// ---------------------------------------------------------------------------
// Prep: (a) pack {relu(w), sig*L2E, sig*mu*L2E, relu(w)*erev} into float4 for
// the three hot matrices; (b) layer-0 input synapse sums [B,H0] (x is shared
// by all K particles and all 6 steps). One kernel, branch on blockIdx.
constexpr int NPACK    = H0 * H0 + H0 * H1 + H1 * H1;  // 53248
constexpr int NPACKBLK = NPACK / 256;                   // 208
__global__ __launch_bounds__(256) void prep_kernel(
    const float* __restrict__ w0,  const float* __restrict__ sig0,
    const float* __restrict__ mu0, const float* __restrict__ erev0,
    const float* __restrict__ iw1, const float* __restrict__ isig1,
    const float* __restrict__ imu1,const float* __restrict__ ierev1,
    const float* __restrict__ w1,  const float* __restrict__ sig1,
    const float* __restrict__ mu1, const float* __restrict__ erev1,
    const float* __restrict__ x,   const float* __restrict__ iw0,
    const float* __restrict__ isig0,const float* __restrict__ imu0,
    const float* __restrict__ ierev0,
    float4* __restrict__ pack0, float4* __restrict__ packi1,
    float4* __restrict__ pack1,
    float* __restrict__ in_num, float* __restrict__ in_den)
{
    __shared__ float xs[IN];
    if (blockIdx.x < NPACKBLK) {
        const int t = blockIdx.x * 256 + threadIdx.x;
        constexpr int N0 = H0 * H0;          // 36864
        constexpr int N1 = H0 * H1;          // 12288
        if (t < N0) {
            const float wv = fmaxf(w0[t], 0.0f);
            pack0[t] = make_float4(wv, sig0[t] * L2E, sig0[t] * mu0[t] * L2E,
                                   wv * erev0[t]);
        } else if (t < N0 + N1) {
            const int u = t - N0;
            const float wv = fmaxf(iw1[u], 0.0f);
            packi1[u] = make_float4(wv, isig1[u] * L2E,
                                    isig1[u] * imu1[u] * L2E, wv * ierev1[u]);
        } else {
            const int u = t - N0 - N1;
            const float wv = fmaxf(w1[u], 0.0f);
            pack1[u] = make_float4(wv, sig1[u] * L2E, sig1[u] * mu1[u] * L2E,
                                   wv * erev1[u]);
        }
    } else {
        const int b = blockIdx.x - NPACKBLK;
        const int h = threadIdx.x;
        if (h < IN) xs[h] = x[b * IN + h];
        __syncthreads();
        if (h < H0) {
            float num = 0.0f, den = 0.0f;
            #pragma unroll 4
            for (int i = 0; i < IN; ++i) {
                const int idx = i * H0 + h;
                const float wv = fmaxf(iw0[idx], 0.0f);
                const float t  = isig0[idx] * L2E * (imu0[idx] - xs[i]);
                const float a  = wv * sig_from_t(t);
                num = fmaf(a, ierev0[idx], num);
                den += a;
            }
            in_num[b * H0 + h] = num;
            in_den[b * H0 + h] = den;
        }
    }
}

// ---------------------------------------------------------------------------
// Layer-0 sweep body: LEN i-values x 4 rows, compile-time trip count.
template <int LEN>
static __device__ __forceinline__ void sweep0_body(
    const float4* __restrict__ pp,      // pack0 + ibase*H0 + h
    const float* vsbase, int ibase,     // &vs[0][0]
    float num[4], float den[4])
{
    #pragma unroll 8
    for (int ii = 0; ii < LEN; ++ii) {
        const float4 p  = pp[(size_t)ii * H0];        // {wv, sig', smu', wv*er}
        const float4 vv = *(const float4*)(vsbase + (ibase + ii) * 4);
        float s;
        s = sig_from_t(fmaf(-p.y, vv.x, p.z));
        num[0] = fmaf(s, p.w, num[0]); den[0] = fmaf(s, p.x, den[0]);
        s = sig_from_t(fmaf(-p.y, vv.y, p.z));
        num[1] = fmaf(s, p.w, num[1]); den[1] = fmaf(s, p.x, den[1]);
        s = sig_from_t(fmaf(-p.y, vv.z, p.z));
        num[2] = fmaf(s, p.w, num[2]); den[2] = fmaf(s, p.x, den[2]);
        s = sig_from_t(fmaf(-p.y, vv.w, p.z));
        num[3] = fmaf(s, p.w, num[3]); den[3] = fmaf(s, p.x, den[3]);
    }
}

// ---------------------------------------------------------------------------
// Fused unfold + output: 256 blocks x 960 threads (15 waves — all in ONE
// block per CU; R4 showed the HW does not co-schedule two 12-wave blocks).
// Each block owns 4 particle rows end-to-end (layer 0, layer 1, weighted
// output contribution via atomics).
//
// Layer 0: subgroup q in 0..4 (192 thr each) handles i-range {40,40,40,40,32}
// for ALL 4 rows; state transposed vs[i][4] so one ds_read_b128 yields all
// rows. Partials reduced via LDS; q<4 threads apply row q's update.
// Layer 1: waves 0..7 split i 8-ways with the same 4-row register reuse.
// Output: per-block softmax over the batch's 64 log-weights, atomicAdd of
// this block's 4-row contribution into out_y (zeroed by hipMemsetAsync).
__global__ __launch_bounds__(960) void fused_unfold_kernel(
    const float* __restrict__ particles,  // [BK, 256]
    const float* __restrict__ noise0,     // [UNF, BK, H0]
    const float* __restrict__ noise1,     // [UNF, BK, H1]
    const float* __restrict__ log_weights,// [B, K]
    const float* __restrict__ gleak0, const float* __restrict__ vleak0,
    const float* __restrict__ cm0,    const float* __restrict__ gdiff0,
    const float* __restrict__ gleak1, const float* __restrict__ vleak1,
    const float* __restrict__ cm1,    const float* __restrict__ gdiff1,
    const float4* __restrict__ pack0,     // [H0*H0]
    const float4* __restrict__ packi1,    // [H0*H1]
    const float4* __restrict__ pack1,     // [H1*H1]
    const float* __restrict__ in_num,     // [B, H0]
    const float* __restrict__ in_den,
    float* __restrict__ outp,             // new_particles region: [BK, 256]
    float* __restrict__ out_y,            // [B, H1] — pre-zeroed
    float* __restrict__ out_lw)           // [B, K]
{
    const int tid = threadIdx.x;
    const int h   = tid % H0;             // 0..191
    const int q   = tid / H0;             // 0..4 (i-split group; q<4 also row)
    const int bk0 = blockIdx.x * 4;
    const int b   = blockIdx.x >> 4;      // batch (16 blocks per batch)
    const int k0  = (blockIdx.x & 15) * 4;// this block's first k within batch

    const int h1  = tid & 63;
    const int qq  = tid >> 6;             // wave id 0..14

    __shared__ __align__(16) float vs[H0][4];     // s0 state, [i][m]
    __shared__ float2 part0[5][4][H0];            // [q][m][h] {num,den}
    __shared__ __align__(16) float v1s[H1][4];    // s1 state, [i][m]
    __shared__ float2 part1[8][4][H1];            // [qq][m][h1]
    __shared__ float  w4[4];                      // softmax weights, this block

    // ---- Softmax weights + log_weights passthrough (wave 0) ----
    if (tid < 64) {
        const float lw = log_weights[b * K + tid];
        out_lw[b * K + tid] = lw;                 // 16x redundant, same value
        float mx = lw;
        #pragma unroll
        for (int o = 32; o > 0; o >>= 1) mx = fmaxf(mx, __shfl_xor(mx, o));
        const float e = __expf(lw - mx);
        float ssum = e;
        #pragma unroll
        for (int o = 32; o > 0; o >>= 1) ssum += __shfl_xor(ssum, o);
        if (tid >= k0 && tid < k0 + 4) w4[tid - k0] = e / ssum;
    }

    // ---- Early layer-1 state loads (hidden behind layer-0 compute) ----
    float nz1[UNF];
    if (tid < 256) {                      // qq in 0..3 = row
        v1s[h1][qq] = particles[(bk0 + qq) * 256 + H0 + h1];
        #pragma unroll
        for (int s = 0; s < UNF; ++s)
            nz1[s] = noise1[s * (BK * H1) + (bk0 + qq) * H1 + h1];
    }

    // ---- Layer 0 setup ----
    float nz[UNF];
    if (q < 4) {
        vs[h][q] = particles[(bk0 + q) * 256 + h];
        #pragma unroll
        for (int s = 0; s < UNF; ++s)
            nz[s] = noise0[s * (BK * H0) + (bk0 + q) * H0 + h];
    }

    const float gl    = fmaxf(gleak0[h], 0.0f);
    const float glvl  = gl * vleak0[h];
    const float cinv  = rcpf(fmaxf(cm0[h], 0.0f) + EPS);
    const float gd    = gdiff0[h] * sqrtf(DT);
    const float innum = in_num[b * H0 + h];
    const float inden = in_den[b * H0 + h];
    __syncthreads();

    // ---- Layer 0 unfold ----
    const int ibase = (q == 4) ? 160 : 40 * q;
    const float4* pp = pack0 + (size_t)ibase * H0 + h;
    for (int step = 0; step < UNF; ++step) {
        float num[4] = {0.f, 0.f, 0.f, 0.f};
        float den[4] = {0.f, 0.f, 0.f, 0.f};
        if (q == 4) sweep0_body<32>(pp, &vs[0][0], ibase, num, den);
        else        sweep0_body<40>(pp, &vs[0][0], ibase, num, den);
        #pragma unroll
        for (int m = 0; m < 4; ++m)
            part0[q][m][h] = make_float2(num[m], den[m]);
        __syncthreads();
        if (q < 4) {                      // thread (q,h) updates row q
            float tn = innum, td = inden;
            #pragma unroll
            for (int j = 0; j < 5; ++j) {
                const float2 t = part0[j][q][h];
                tn += t.x; td += t.y;
            }
            const float vh = vs[h][q];
            const float d  = (glvl + tn - (gl + td) * vh) * cinv;
            vs[h][q] = fmaf(gd, nz[step], fmaf(d, DT, vh));
        }
        __syncthreads();
    }

    // s0 -> new_particles[:, :H0] (own value; no barrier needed)
    if (q < 4) outp[(bk0 + q) * 256 + h] = vs[h][q];

    // ---- Layer 1 (same 4 rows; s0 in LDS) ----
    float gl1 = 0.f, glvl1 = 0.f, cinv1 = 0.f, gd1 = 0.f;
    float in1n[4] = {0.f, 0.f, 0.f, 0.f};
    float in1d[4] = {0.f, 0.f, 0.f, 0.f};
    if (tid < 512) {                      // waves 0..7: i-split over 192
        gl1   = fmaxf(gleak1[h1], 0.0f);
        glvl1 = gl1 * vleak1[h1];
        cinv1 = rcpf(fmaxf(cm1[h1], 0.0f) + EPS);
        gd1   = gdiff1[h1] * sqrtf(DT);
        #pragma unroll 4
        for (int ii = 0; ii < 24; ++ii) {
            const int i = qq * 24 + ii;
            const float4 p  = packi1[i * H1 + h1];
            const float4 vv = *(const float4*)&vs[i][0];
            float s;
            s = sig_from_t(fmaf(-p.y, vv.x, p.z));
            in1n[0] = fmaf(s, p.w, in1n[0]); in1d[0] = fmaf(s, p.x, in1d[0]);
            s = sig_from_t(fmaf(-p.y, vv.y, p.z));
            in1n[1] = fmaf(s, p.w, in1n[1]); in1d[1] = fmaf(s, p.x, in1d[1]);
            s = sig_from_t(fmaf(-p.y, vv.z, p.z));
            in1n[2] = fmaf(s, p.w, in1n[2]); in1d[2] = fmaf(s, p.x, in1d[2]);
            s = sig_from_t(fmaf(-p.y, vv.w, p.z));
            in1n[3] = fmaf(s, p.w, in1n[3]); in1d[3] = fmaf(s, p.x, in1d[3]);
        }
    }
    __syncthreads();

    for (int step = 0; step < UNF; ++step) {
        if (tid < 512) {
            float num[4], den[4];
            #pragma unroll
            for (int m = 0; m < 4; ++m) { num[m] = in1n[m]; den[m] = in1d[m]; }
            #pragma unroll
            for (int ii = 0; ii < 8; ++ii) {
                const int i = qq * 8 + ii;
                const float4 p  = pack1[i * H1 + h1];
                const float4 vv = *(const float4*)&v1s[i][0];
                float s;
                s = sig_from_t(fmaf(-p.y, vv.x, p.z));
                num[0] = fmaf(s, p.w, num[0]); den[0] = fmaf(s, p.x, den[0]);
                s = sig_from_t(fmaf(-p.y, vv.y, p.z));
                num[1] = fmaf(s, p.w, num[1]); den[1] = fmaf(s, p.x, den[1]);
                s = sig_from_t(fmaf(-p.y, vv.z, p.z));
                num[2] = fmaf(s, p.w, num[2]); den[2] = fmaf(s, p.x, den[2]);
                s = sig_from_t(fmaf(-p.y, vv.w, p.z));
                num[3] = fmaf(s, p.w, num[3]); den[3] = fmaf(s, p.x, den[3]);
            }
            #pragma unroll
            for (int m = 0; m < 4; ++m)
                part1[qq][m][h1] = make_float2(num[m], den[m]);
        }
        __syncthreads();
        if (tid < 256) {                  // row qq, element h1
            float tn = 0.f, td = 0.f;
            #pragma unroll
            for (int j = 0; j < 8; ++j) {
                const float2 t = part1[j][qq][h1];
                tn += t.x; td += t.y;
            }
            const float vh = v1s[h1][qq];
            const float d  = (glvl1 + tn - (gl1 + td) * vh) * cinv1;
            v1s[h1][qq] = fmaf(gd1, nz1[step], fmaf(d, DT, vh));
        }
        __syncthreads();
    }

    if (tid < 256)
        outp[(bk0 + qq) * 256 + H0 + h1] = v1s[h1][qq];  // s1 -> [:, H0:]

    // ---- Weighted-mean contribution of this block's 4 particles ----
    if (tid < 64) {
        const float acc = w4[0] * v1s[tid][0] + w4[1] * v1s[tid][1]
                        + w4[2] * v1s[tid][2] + w4[3] * v1s[tid][3];
        atomicAdd(&out_y[b * H1 + tid], acc);
    }
}

// ---------------------------------------------------------------------------
extern "C" void kernel_launch(void* const* d_in, const int* in_sizes, int n_in,
                              void* d_out, int out_size, void* d_ws, size_t ws_size,
                              hipStream_t stream) {
    const float* x           = (const float*)d_in[0];
    const float* particles   = (const float*)d_in[1];
    const float* log_weights = (const float*)d_in[2];
    const float* noise0      = (const float*)d_in[3];
    const float* noise1      = (const float*)d_in[4];
    const float* gleak0 = (const float*)d_in[5];
    const float* vleak0 = (const float*)d_in[6];
    const float* cm0    = (const float*)d_in[7];
    const float* iw0    = (const float*)d_in[8];
    const float* isig0  = (const float*)d_in[9];
    const float* imu0   = (const float*)d_in[10];
    const float* ierev0 = (const float*)d_in[11];
    const float* w0     = (const float*)d_in[12];
    const float* sig0   = (const float*)d_in[13];
    const float* mu0    = (const float*)d_in[14];
    const float* erev0  = (const float*)d_in[15];
    const float* gdiff0 = (const float*)d_in[16];
    const float* gleak1 = (const float*)d_in[17];
    const float* vleak1 = (const float*)d_in[18];
    const float* cm1    = (const float*)d_in[19];
    const float* iw1    = (const float*)d_in[20];
    const float* isig1  = (const float*)d_in[21];
    const float* imu1   = (const float*)d_in[22];
    const float* ierev1 = (const float*)d_in[23];
    const float* w1     = (const float*)d_in[24];
    const float* sig1   = (const float*)d_in[25];
    const float* mu1    = (const float*)d_in[26];
    const float* erev1  = (const float*)d_in[27];
    const float* gdiff1 = (const float*)d_in[28];

    float* out    = (float*)d_out;
    float* out_y  = out;                       // [B, H1] = 1024
    float* out_np = out + B * H1;              // [BK, 256] = 262144
    float* out_lw = out + B * H1 + BK * 256;   // [B, K]   = 1024

    // Workspace layout (floats): pack0 | packi1 | pack1 | in_num0 | in_den0
    float* ws      = (float*)d_ws;
    float4* pack0  = (float4*)(ws);                       // 36864 float4
    float4* packi1 = (float4*)(ws + 4 * 36864);           // 12288 float4
    float4* pack1  = (float4*)(ws + 4 * (36864 + 12288)); //  4096 float4
    float*  in_num0 = ws + 4 * (36864 + 12288 + 4096);    // [B, H0]
    float*  in_den0 = in_num0 + B * H0;                   // [B, H0]

    // out_y accumulated via atomics — zero it (d_out is poisoned pre-call).
    hipMemsetAsync(out_y, 0, B * H1 * sizeof(float), stream);

    prep_kernel<<<NPACKBLK + B, 256, 0, stream>>>(
        w0, sig0, mu0, erev0, iw1, isig1, imu1, ierev1, w1, sig1, mu1, erev1,
        x, iw0, isig0, imu0, ierev0,
        pack0, packi1, pack1, in_num0, in_den0);

    fused_unfold_kernel<<<BK / 4, 960, 0, stream>>>(
        particles, noise0, noise1, log_weights,
        gleak0, vleak0, cm0, gdiff0,
        gleak1, vleak1, cm1, gdiff1,
        pack0, packi1, pack1, in_num0, in_den0,
        out_np, out_y, out_lw);
}